// Round 4
// baseline (112.364 us; speedup 1.0000x reference)
//
#include <hip/hip_runtime.h>

// KDE gaussian: out[k][b] = (1/(LEN*bw*sqrt(2pi))) * sum_i exp(-0.5*((x[b][i]-c[k])/bw)^2)
// bw = 0.1. Folded: 2^(-(S*x - S*c)^2), S = sqrt(0.5*log2(e))/bw.
// Per pair: v_fma (t = x*S - cs), v_mul (t*t), v_exp (neg input modifier), v_add.
// Wave-uniform broadcast loads (no LDS, no barriers) + explicit distance-1
// register prefetch so each wave overlaps next loads with current compute.
// 2048 blocks = 8 blocks/CU for TLP on top of the in-wave ILP.

constexpr int KPTS  = 256;  // grid points == blockDim.x
constexpr int CHUNK = 256;  // samples per block
constexpr int ITER  = CHUNK / 16;

__global__ __launch_bounds__(KPTS) void kde_kernel(
    const float* __restrict__ data, const float* __restrict__ c_X,
    float* __restrict__ out, int LEN, int B) {
  const int k = threadIdx.x;
  const float S = 8.49321736f;  // sqrt(0.5*log2(e)) / 0.1

  const float4* p = (const float4*)(data + (size_t)blockIdx.y * LEN +
                                    (size_t)blockIdx.x * CHUNK);
  const float ncs = -(c_X[k] * S);  // -S*c, per-lane

  float2 a0 = {0.f, 0.f}, a1 = {0.f, 0.f}, a2 = {0.f, 0.f}, a3 = {0.f, 0.f};
  float2 a4 = {0.f, 0.f}, a5 = {0.f, 0.f}, a6 = {0.f, 0.f}, a7 = {0.f, 0.f};

  // Prime the pipeline.
  float4 c0 = p[0], c1 = p[1], c2 = p[2], c3 = p[3];

#define KDE_BODY(x0, x1, x2, x3)                                   \
  do {                                                             \
    float t0 = fmaf((x0).x, S, ncs), t1 = fmaf((x0).y, S, ncs);    \
    float t2 = fmaf((x0).z, S, ncs), t3 = fmaf((x0).w, S, ncs);    \
    float t4 = fmaf((x1).x, S, ncs), t5 = fmaf((x1).y, S, ncs);    \
    float t6 = fmaf((x1).z, S, ncs), t7 = fmaf((x1).w, S, ncs);    \
    float t8 = fmaf((x2).x, S, ncs), t9 = fmaf((x2).y, S, ncs);    \
    float ta = fmaf((x2).z, S, ncs), tb = fmaf((x2).w, S, ncs);    \
    float tc = fmaf((x3).x, S, ncs), td = fmaf((x3).y, S, ncs);    \
    float te = fmaf((x3).z, S, ncs), tf = fmaf((x3).w, S, ncs);    \
    a0.x += __builtin_amdgcn_exp2f(-(t0 * t0));                    \
    a0.y += __builtin_amdgcn_exp2f(-(t1 * t1));                    \
    a1.x += __builtin_amdgcn_exp2f(-(t2 * t2));                    \
    a1.y += __builtin_amdgcn_exp2f(-(t3 * t3));                    \
    a2.x += __builtin_amdgcn_exp2f(-(t4 * t4));                    \
    a2.y += __builtin_amdgcn_exp2f(-(t5 * t5));                    \
    a3.x += __builtin_amdgcn_exp2f(-(t6 * t6));                    \
    a3.y += __builtin_amdgcn_exp2f(-(t7 * t7));                    \
    a4.x += __builtin_amdgcn_exp2f(-(t8 * t8));                    \
    a4.y += __builtin_amdgcn_exp2f(-(t9 * t9));                    \
    a5.x += __builtin_amdgcn_exp2f(-(ta * ta));                    \
    a5.y += __builtin_amdgcn_exp2f(-(tb * tb));                    \
    a6.x += __builtin_amdgcn_exp2f(-(tc * tc));                    \
    a6.y += __builtin_amdgcn_exp2f(-(td * td));                    \
    a7.x += __builtin_amdgcn_exp2f(-(te * te));                    \
    a7.y += __builtin_amdgcn_exp2f(-(tf * tf));                    \
  } while (0)

  for (int i = 0; i < ITER - 1; ++i) {
    // Prefetch next 16 samples while computing current 16.
    float4 n0 = p[4 * i + 4], n1 = p[4 * i + 5];
    float4 n2 = p[4 * i + 6], n3 = p[4 * i + 7];
    KDE_BODY(c0, c1, c2, c3);
    c0 = n0; c1 = n1; c2 = n2; c3 = n3;
  }
  KDE_BODY(c0, c1, c2, c3);  // peeled last iteration
#undef KDE_BODY

  const float norm = 3.98942280f / (float)LEN;  // (1/bw)*(1/sqrt(2pi))/LEN
  float2 s01 = {a0.x + a1.x, a0.y + a1.y};
  float2 s23 = {a2.x + a3.x, a2.y + a3.y};
  float2 s45 = {a4.x + a5.x, a4.y + a5.y};
  float2 s67 = {a6.x + a7.x, a6.y + a7.y};
  float2 s = {s01.x + s23.x + s45.x + s67.x, s01.y + s23.y + s45.y + s67.y};
  atomicAdd(&out[(size_t)k * B + blockIdx.y], (s.x + s.y) * norm);
}

extern "C" void kernel_launch(void* const* d_in, const int* in_sizes, int n_in,
                              void* d_out, int out_size, void* d_ws, size_t ws_size,
                              hipStream_t stream) {
  const float* data = (const float*)d_in[0];
  // d_in[1] is `dim` (= -1): last-axis reduction, data already [B, LEN]
  const float* c_X  = (const float*)d_in[2];
  float* out        = (float*)d_out;

  const int B   = 16;
  const int LEN = in_sizes[0] / B;  // 32768

  hipMemsetAsync(d_out, 0, (size_t)out_size * sizeof(float), stream);

  dim3 grid(LEN / CHUNK, B);        // (128, 16) = 2048 blocks, 8 blocks/CU
  kde_kernel<<<grid, KPTS, 0, stream>>>(data, c_X, out, LEN, B);
}

// Round 5
// 79.807 us; speedup vs baseline: 1.4079x; 1.4079x over previous
//
#include <hip/hip_runtime.h>

// KDE gaussian: out[k][b] = (1/(LEN*bw*sqrt(2pi))) * sum_i exp(-0.5*((x[b][i]-c[k])/bw)^2)
// bw = 0.1. Folded: 2^(-(S*x - S*c)^2), S = sqrt(0.5*log2(e))/bw.
// Stage 1: R3 structure (wave-uniform broadcast loads -> SGPRs, no LDS/barriers,
//          16 independent exp chains), but partials go to a PRIVATE d_ws slice
//          with a plain coalesced store — no global atomics. (R1-R4 showed kernel
//          time tracked atomic count: device-scope fp32 atomicAdd writes through
//          to HBM, 32B each, serializing per-address on only 4096 targets.)
// Stage 2: tiny reduce over the 64 per-row partials -> d_out (fully overwrites,
//          so no memset needed).

constexpr int KPTS   = 256;  // grid points == blockDim.x
constexpr int CHUNK  = 512;  // samples per block
constexpr int NCHUNK = 32768 / CHUNK;  // 64 partials per (b) row

__global__ __launch_bounds__(KPTS) void kde_partial(
    const float* __restrict__ data, const float* __restrict__ c_X,
    float* __restrict__ ws, int LEN) {
  const int k = threadIdx.x;
  const float S = 8.49321736f;  // sqrt(0.5*log2(e)) / 0.1

  const float* src = data + (size_t)blockIdx.y * LEN + (size_t)blockIdx.x * CHUNK;
  const float ncs = -(c_X[k] * S);  // -S*c, per-lane

  float2 a0 = {0.f, 0.f}, a1 = {0.f, 0.f}, a2 = {0.f, 0.f}, a3 = {0.f, 0.f};
  float2 a4 = {0.f, 0.f}, a5 = {0.f, 0.f}, a6 = {0.f, 0.f}, a7 = {0.f, 0.f};

  for (int i = 0; i < CHUNK; i += 16) {
    // Uniform addresses (blockIdx + loop counter only) -> scalar s_load path.
    const float4* p = (const float4*)(src + i);
    float4 x0 = p[0], x1 = p[1], x2 = p[2], x3 = p[3];

    float t0 = fmaf(x0.x, S, ncs), t1 = fmaf(x0.y, S, ncs);
    float t2 = fmaf(x0.z, S, ncs), t3 = fmaf(x0.w, S, ncs);
    float t4 = fmaf(x1.x, S, ncs), t5 = fmaf(x1.y, S, ncs);
    float t6 = fmaf(x1.z, S, ncs), t7 = fmaf(x1.w, S, ncs);
    float t8 = fmaf(x2.x, S, ncs), t9 = fmaf(x2.y, S, ncs);
    float ta = fmaf(x2.z, S, ncs), tb = fmaf(x2.w, S, ncs);
    float tc = fmaf(x3.x, S, ncs), td = fmaf(x3.y, S, ncs);
    float te = fmaf(x3.z, S, ncs), tf = fmaf(x3.w, S, ncs);

    a0.x += __builtin_amdgcn_exp2f(-(t0 * t0));
    a0.y += __builtin_amdgcn_exp2f(-(t1 * t1));
    a1.x += __builtin_amdgcn_exp2f(-(t2 * t2));
    a1.y += __builtin_amdgcn_exp2f(-(t3 * t3));
    a2.x += __builtin_amdgcn_exp2f(-(t4 * t4));
    a2.y += __builtin_amdgcn_exp2f(-(t5 * t5));
    a3.x += __builtin_amdgcn_exp2f(-(t6 * t6));
    a3.y += __builtin_amdgcn_exp2f(-(t7 * t7));
    a4.x += __builtin_amdgcn_exp2f(-(t8 * t8));
    a4.y += __builtin_amdgcn_exp2f(-(t9 * t9));
    a5.x += __builtin_amdgcn_exp2f(-(ta * ta));
    a5.y += __builtin_amdgcn_exp2f(-(tb * tb));
    a6.x += __builtin_amdgcn_exp2f(-(tc * tc));
    a6.y += __builtin_amdgcn_exp2f(-(td * td));
    a7.x += __builtin_amdgcn_exp2f(-(te * te));
    a7.y += __builtin_amdgcn_exp2f(-(tf * tf));
  }

  float2 s01 = {a0.x + a1.x, a0.y + a1.y};
  float2 s23 = {a2.x + a3.x, a2.y + a3.y};
  float2 s45 = {a4.x + a5.x, a4.y + a5.y};
  float2 s67 = {a6.x + a7.x, a6.y + a7.y};
  float s = (s01.x + s23.x) + (s45.x + s67.x) + (s01.y + s23.y) + (s45.y + s67.y);

  // Private partial slot: ws[(b*NCHUNK + chunk)*KPTS + k] — one coalesced store.
  ws[((size_t)blockIdx.y * NCHUNK + blockIdx.x) * KPTS + k] = s;
}

__global__ __launch_bounds__(KPTS) void kde_reduce(
    const float* __restrict__ ws, float* __restrict__ out, int LEN, int B) {
  const int k = threadIdx.x;
  const int b = blockIdx.x;
  const float* p = ws + (size_t)b * NCHUNK * KPTS + k;
  float s0 = 0.f, s1 = 0.f, s2 = 0.f, s3 = 0.f;
#pragma unroll
  for (int i = 0; i < NCHUNK; i += 4) {
    s0 += p[(i + 0) * KPTS];
    s1 += p[(i + 1) * KPTS];
    s2 += p[(i + 2) * KPTS];
    s3 += p[(i + 3) * KPTS];
  }
  const float norm = 3.98942280f / (float)LEN;  // (1/bw)*(1/sqrt(2pi))/LEN
  out[(size_t)k * B + b] = ((s0 + s1) + (s2 + s3)) * norm;
}

extern "C" void kernel_launch(void* const* d_in, const int* in_sizes, int n_in,
                              void* d_out, int out_size, void* d_ws, size_t ws_size,
                              hipStream_t stream) {
  const float* data = (const float*)d_in[0];
  // d_in[1] is `dim` (= -1): last-axis reduction, data already [B, LEN]
  const float* c_X  = (const float*)d_in[2];
  float* out        = (float*)d_out;
  float* ws         = (float*)d_ws;

  const int B   = 16;
  const int LEN = in_sizes[0] / B;  // 32768

  dim3 grid(LEN / CHUNK, B);        // (64, 16) = 1024 blocks
  kde_partial<<<grid, KPTS, 0, stream>>>(data, c_X, ws, LEN);
  kde_reduce<<<dim3(B), KPTS, 0, stream>>>(ws, out, LEN, B);
}

// Round 6
// 75.644 us; speedup vs baseline: 1.4854x; 1.0550x over previous
//
#include <hip/hip_runtime.h>

// KDE gaussian: out[k][b] = (1/(LEN*bw*sqrt(2pi))) * sum_i exp(-0.5*((x[b][i]-c[k])/bw)^2)
// bw = 0.1. Folded: 2^(-(S*x - S*c)^2), S = sqrt(0.5*log2(e))/bw.
// Stage 1: wave-uniform broadcast loads (s_load path, no LDS/barriers), float2
//          math to shape v_pk_fma_f32/v_pk_mul_f32/v_pk_add_f32 (halves non-trans
//          issue), 2048 blocks for full-occupancy TLP (atomics gone -> no penalty),
//          partials to private d_ws slices with plain coalesced stores.
// Stage 2: tiny reduce over 128 per-row partials -> d_out (no memset needed).

constexpr int KPTS   = 256;            // grid points == blockDim.x
constexpr int CHUNK  = 256;            // samples per block
constexpr int NCHUNK = 32768 / CHUNK;  // 128 partials per b-row

__global__ __launch_bounds__(KPTS) void kde_partial(
    const float* __restrict__ data, const float* __restrict__ c_X,
    float* __restrict__ ws, int LEN) {
  const int k = threadIdx.x;
  const float S = 8.49321736f;  // sqrt(0.5*log2(e)) / 0.1

  const float* src = data + (size_t)blockIdx.y * LEN + (size_t)blockIdx.x * CHUNK;
  const float ncs = -(c_X[k] * S);  // -S*c, per-lane
  const float2 S2 = {S, S};
  const float2 N2 = {ncs, ncs};

  float2 a0 = {0.f, 0.f}, a1 = {0.f, 0.f}, a2 = {0.f, 0.f}, a3 = {0.f, 0.f};
  float2 a4 = {0.f, 0.f}, a5 = {0.f, 0.f}, a6 = {0.f, 0.f}, a7 = {0.f, 0.f};

#pragma unroll 2
  for (int i = 0; i < CHUNK; i += 16) {
    // Uniform addresses (blockIdx + loop counter only) -> scalar s_load path.
    const float4* p = (const float4*)(src + i);
    float4 x0 = p[0], x1 = p[1], x2 = p[2], x3 = p[3];

    float2 v0 = {x0.x, x0.y}, v1 = {x0.z, x0.w};
    float2 v2 = {x1.x, x1.y}, v3 = {x1.z, x1.w};
    float2 v4 = {x2.x, x2.y}, v5 = {x2.z, x2.w};
    float2 v6 = {x3.x, x3.y}, v7 = {x3.z, x3.w};

    // t = S*x - S*c  (v_pk_fma_f32 after contraction), q = t*t (v_pk_mul_f32)
    float2 t0 = v0 * S2 + N2, t1 = v1 * S2 + N2;
    float2 t2 = v2 * S2 + N2, t3 = v3 * S2 + N2;
    float2 t4 = v4 * S2 + N2, t5 = v5 * S2 + N2;
    float2 t6 = v6 * S2 + N2, t7 = v7 * S2 + N2;
    float2 q0 = t0 * t0, q1 = t1 * t1, q2 = t2 * t2, q3 = t3 * t3;
    float2 q4 = t4 * t4, q5 = t5 * t5, q6 = t6 * t6, q7 = t7 * t7;

    float2 e0 = {__builtin_amdgcn_exp2f(-q0.x), __builtin_amdgcn_exp2f(-q0.y)};
    float2 e1 = {__builtin_amdgcn_exp2f(-q1.x), __builtin_amdgcn_exp2f(-q1.y)};
    float2 e2 = {__builtin_amdgcn_exp2f(-q2.x), __builtin_amdgcn_exp2f(-q2.y)};
    float2 e3 = {__builtin_amdgcn_exp2f(-q3.x), __builtin_amdgcn_exp2f(-q3.y)};
    float2 e4 = {__builtin_amdgcn_exp2f(-q4.x), __builtin_amdgcn_exp2f(-q4.y)};
    float2 e5 = {__builtin_amdgcn_exp2f(-q5.x), __builtin_amdgcn_exp2f(-q5.y)};
    float2 e6 = {__builtin_amdgcn_exp2f(-q6.x), __builtin_amdgcn_exp2f(-q6.y)};
    float2 e7 = {__builtin_amdgcn_exp2f(-q7.x), __builtin_amdgcn_exp2f(-q7.y)};

    a0 = a0 + e0; a1 = a1 + e1; a2 = a2 + e2; a3 = a3 + e3;  // v_pk_add_f32
    a4 = a4 + e4; a5 = a5 + e5; a6 = a6 + e6; a7 = a7 + e7;
  }

  float2 s01 = a0 + a1, s23 = a2 + a3, s45 = a4 + a5, s67 = a6 + a7;
  float2 s = (s01 + s23) + (s45 + s67);

  // Private partial slot — one coalesced store, no atomics.
  ws[((size_t)blockIdx.y * NCHUNK + blockIdx.x) * KPTS + k] = s.x + s.y;
}

__global__ __launch_bounds__(KPTS) void kde_reduce(
    const float* __restrict__ ws, float* __restrict__ out, int LEN, int B) {
  const int k = threadIdx.x;
  const int b = blockIdx.x;
  const float* p = ws + (size_t)b * NCHUNK * KPTS + k;
  float s0 = 0.f, s1 = 0.f, s2 = 0.f, s3 = 0.f;
  float s4 = 0.f, s5 = 0.f, s6 = 0.f, s7 = 0.f;
  for (int i = 0; i < NCHUNK; i += 8) {
    s0 += p[(i + 0) * KPTS];
    s1 += p[(i + 1) * KPTS];
    s2 += p[(i + 2) * KPTS];
    s3 += p[(i + 3) * KPTS];
    s4 += p[(i + 4) * KPTS];
    s5 += p[(i + 5) * KPTS];
    s6 += p[(i + 6) * KPTS];
    s7 += p[(i + 7) * KPTS];
  }
  const float norm = 3.98942280f / (float)LEN;  // (1/bw)*(1/sqrt(2pi))/LEN
  out[(size_t)k * B + b] = (((s0 + s1) + (s2 + s3)) + ((s4 + s5) + (s6 + s7))) * norm;
}

extern "C" void kernel_launch(void* const* d_in, const int* in_sizes, int n_in,
                              void* d_out, int out_size, void* d_ws, size_t ws_size,
                              hipStream_t stream) {
  const float* data = (const float*)d_in[0];
  // d_in[1] is `dim` (= -1): last-axis reduction, data already [B, LEN]
  const float* c_X  = (const float*)d_in[2];
  float* out        = (float*)d_out;
  float* ws         = (float*)d_ws;

  const int B   = 16;
  const int LEN = in_sizes[0] / B;  // 32768

  dim3 grid(LEN / CHUNK, B);        // (128, 16) = 2048 blocks -> 32 waves/CU nominal
  kde_partial<<<grid, KPTS, 0, stream>>>(data, c_X, ws, LEN);
  kde_reduce<<<dim3(B), KPTS, 0, stream>>>(ws, out, LEN, B);
}